// Round 8
// baseline (391.184 us; speedup 1.0000x reference)
//
#include <hip/hip_runtime.h>
#include <hip/hip_bf16.h>

// TelephoneAttentionBlock: x[4,4096,1024] fp32 -> RMSNorm -> QKV (bf16 MFMA GEMM)
// -> windowed block attention (16 heads, dh=64, window 128) -> Wo GEMM + residual -> fp32 out.
// Round 8: GEMM LDS-traffic cut — B fragments direct from global (L2-resident weights,
// never staged), 4Mx2N wave map (A redundancy 4x->2x), A-only 2-buffer LDS (64KB).
// LDS/tile: 224KB -> 96KB; MFMA becomes critical path. Transposes fused into one launch.

typedef __attribute__((ext_vector_type(8))) short s8v;   // 8 bf16 (4 VGPRs)
typedef __attribute__((ext_vector_type(4))) float f4v;   // MFMA accumulator

#define MFMA_BF16(A, B, C) __builtin_amdgcn_mfma_f32_16x16x32_bf16((A), (B), (C), 0, 0, 0)

static __device__ __forceinline__ void gload_lds16(const void* g, void* l) {
    // async global->LDS, 16B per lane; LDS dest = wave-uniform base + lane*16
    __builtin_amdgcn_global_load_lds((const __attribute__((address_space(1))) void*)g,
                                     (__attribute__((address_space(3))) void*)l, 16, 0, 0);
}

static __device__ __forceinline__ unsigned short f2bf(float f) {
    return __builtin_bit_cast(unsigned short, __float2bfloat16(f));
}

// ---------------- weight cast + transpose (both weights in one launch) ----------------
// in[K][N] fp32 -> out[N][K] bf16. Blocks [0, nb1) do Wqkv (1024x3072); rest do Wo (1024x1024).
__global__ __launch_bounds__(256) void transpose_cast_kernel(const float* __restrict__ Wqkv,
                                                             unsigned short* __restrict__ WqkvT,
                                                             const float* __restrict__ Wo,
                                                             unsigned short* __restrict__ WoT) {
    const int K = 1024;
    int nb1 = (K >> 5) * (3072 >> 5);          // 32x96 = 3072 blocks
    const float* in;
    unsigned short* out;
    int N, bidx;
    if (blockIdx.x < (unsigned)nb1) {
        in = Wqkv; out = WqkvT; N = 3072; bidx = blockIdx.x;
    } else {
        in = Wo; out = WoT; N = 1024; bidx = blockIdx.x - nb1;
    }
    __shared__ float tile[32][33];
    int nbk = K >> 5;
    int bk = bidx % nbk;
    int bn = bidx / nbk;
    int tx = threadIdx.x & 31, ty = threadIdx.x >> 5;
#pragma unroll
    for (int i = 0; i < 4; i++) {
        int r = ty + i * 8;
        tile[r][tx] = in[(size_t)(bk * 32 + r) * N + bn * 32 + tx];
    }
    __syncthreads();
#pragma unroll
    for (int i = 0; i < 4; i++) {
        int r = ty + i * 8;
        out[(size_t)(bn * 32 + r) * K + bk * 32 + tx] = f2bf(tile[tx][r]);
    }
}

// ---------------- RMSNorm: x fp32 [M][1024] -> xn bf16 ----------------
__global__ __launch_bounds__(256) void rmsnorm_kernel(const float* __restrict__ x,
                                                      const float* __restrict__ g,
                                                      unsigned short* __restrict__ xn) {
    const int D = 1024;
    int row = blockIdx.x;
    int t = threadIdx.x;
    float4 v = ((const float4*)(x + (size_t)row * D))[t];
    float ss = v.x * v.x + v.y * v.y + v.z * v.z + v.w * v.w;
#pragma unroll
    for (int off = 32; off >= 1; off >>= 1) ss += __shfl_xor(ss, off, 64);
    __shared__ float partials[4];
    if ((t & 63) == 0) partials[t >> 6] = ss;
    __syncthreads();
    float tot = partials[0] + partials[1] + partials[2] + partials[3];
    float scale = rsqrtf(tot * (1.0f / D) + 1e-6f);
    float4 gv = ((const float4*)g)[t];
    ushort4 o;
    o.x = f2bf(v.x * scale * gv.x);
    o.y = f2bf(v.y * scale * gv.y);
    o.z = f2bf(v.z * scale * gv.z);
    o.w = f2bf(v.w * scale * gv.w);
    ((ushort4*)xn)[(size_t)row * (D / 4) + t] = o;
}

// ---------------- GEMM 256x256, BK=64: A-only LDS (2x32KB), B direct from global ----------------
// C[M][N] = A[M][K] * Bt[N][K]^T. MODE 0: C -> bf16. MODE 1: C -> fp32 = resid + acc.
// 512 threads = 8 waves as 4M x 2N; per-wave output 64x128 (acc 4x8 f4v = 128 regs).
// LDS: A only, double-buffered 2 x 32KB (256 rows x 128B), R3's proven swizzle
// (slot ^= row&7 via pre-swizzled global src; read byte c0 = (hl*16)^((ll&7)*16), kk -> ^64).
// B fragments: 16 x 64B-segment global loads per tile per wave, L2-served (weights are
// 2-6MB, L2-resident). Per-tile LDS traffic 96KB (was 224KB) -> MFMA-bound.
// Sync: 1 x {lgkmcnt(0) [WAR], vmcnt(0) [~free: B-use auto-waits drained A-stage first,
// in-order retire], s_barrier} per K-tile.
template <int MODE>
__global__ __launch_bounds__(512, 2) void gemm256_kernel(const unsigned short* __restrict__ A,
                                                         const unsigned short* __restrict__ Bt,
                                                         unsigned short* __restrict__ Cb,
                                                         float* __restrict__ Cf,
                                                         const float* __restrict__ resid,
                                                         int M, int N, int K) {
    __shared__ __align__(16) char lds_s[65536];

    const int nbn = N >> 8;
    const int nwg = (M >> 8) * nbn;
    int bid = blockIdx.x;
    int cpx = nwg >> 3;                        // grids are multiples of 8
    int wg = (bid & 7) * cpx + (bid >> 3);     // XCD-aware swizzle (bijective)
    int bm = wg / nbn, bn = wg % nbn;

    int tid = threadIdx.x, lane = tid & 63, w = tid >> 6;
    int wm = w >> 1, wn = w & 1;               // wave tile: rows wm*64, cols wn*128
    int hl = lane >> 4, ll = lane & 15;

    const unsigned short* Ab = A + (size_t)bm * 256 * K;
    const unsigned short* Bb = Bt + (size_t)bn * 256 * K;

    // A staging lane geometry (R3): 8 rows x 8 swizzled 16B slots per 64 lanes
    int srow = lane >> 3;                       // row within 8-row chunk
    int scol = ((lane & 7) ^ srow) * 8;         // pre-swizzled source col (elems)
    const unsigned short* gA = Ab + (size_t)srow * K + scol;

    // A read-side base: row = wm*64 + m*16 + ll; kk=1 -> c0 ^ 64
    int c0 = (hl * 16) ^ ((ll & 7) * 16);
    const char* ldsA = lds_s + (wm * 64 + ll) * 128;

    // B read base: row (output col) = wn*128 + nf*16 + ll; k-offset hl*8 within 32-chunk
    const unsigned short* gB = Bb + (size_t)(wn * 128 + ll) * K + hl * 8;

    const int NT = K >> 6;                      // 16 K-tiles for K=1024

    f4v acc[4][8] = {};

#define STAGE_A(t_) do {                                                                  \
        char* l_ = lds_s + ((t_) & 1) * 32768 + w * 1024;                                 \
        const unsigned short* g_ = gA + (t_) * 64;                                        \
        gload_lds16(g_ + (size_t)(w * 8) * K, l_);                                        \
        gload_lds16(g_ + (size_t)(64 + w * 8) * K, l_ + 8192);                            \
        gload_lds16(g_ + (size_t)(128 + w * 8) * K, l_ + 16384);                          \
        gload_lds16(g_ + (size_t)(192 + w * 8) * K, l_ + 24576);                          \
    } while (0)

    // prologue
    STAGE_A(0);
    asm volatile("s_waitcnt vmcnt(0)" ::: "memory");
    asm volatile("s_barrier" ::: "memory");

    for (int t = 0; t < NT; t++) {
        if (t + 1 < NT) STAGE_A(t + 1);         // into buf[(t+1)&1]; readers drained t-1
        const char* bufA = ldsA + (t & 1) * 32768;
        // A fragments from LDS
        s8v af[4][2];
#pragma unroll
        for (int m = 0; m < 4; m++) {
            af[m][0] = *(const s8v*)(bufA + m * 2048 + c0);
            af[m][1] = *(const s8v*)(bufA + m * 2048 + (c0 ^ 64));
        }
        // B fragments direct from global (L2)
        s8v bf0[8], bf1[8];
        const unsigned short* gBt = gB + t * 64;
#pragma unroll
        for (int nf = 0; nf < 8; nf++) bf0[nf] = *(const s8v*)(gBt + (size_t)nf * 16 * K);
#pragma unroll
        for (int nf = 0; nf < 8; nf++) bf1[nf] = *(const s8v*)(gBt + (size_t)nf * 16 * K + 32);
        __builtin_amdgcn_s_setprio(1);
#pragma unroll
        for (int m = 0; m < 4; m++)
#pragma unroll
            for (int nf = 0; nf < 8; nf++)
                acc[m][nf] = MFMA_BF16(af[m][0], bf0[nf], acc[m][nf]);
#pragma unroll
        for (int m = 0; m < 4; m++)
#pragma unroll
            for (int nf = 0; nf < 8; nf++)
                acc[m][nf] = MFMA_BF16(af[m][1], bf1[nf], acc[m][nf]);
        __builtin_amdgcn_s_setprio(0);
        if (t + 1 < NT) {
            // lgkmcnt(0): my ds_reads of buf[t&1] done (WAR for next STAGE_A);
            // vmcnt(0): A-stage(t+1) done (in-order retire: B uses already drained it)
            asm volatile("s_waitcnt vmcnt(0) lgkmcnt(0)" ::: "memory");
            asm volatile("s_barrier" ::: "memory");
        }
    }
#undef STAGE_A

    // epilogue: C write
    int crow0 = bm * 256 + wm * 64;
    int ccol0 = bn * 256 + wn * 128;
#pragma unroll
    for (int m = 0; m < 4; m++) {
#pragma unroll
        for (int r = 0; r < 4; r++) {
            int row = crow0 + m * 16 + hl * 4 + r;
#pragma unroll
            for (int nf = 0; nf < 8; nf++) {
                int col = ccol0 + nf * 16 + ll;
                float val = acc[m][nf][r];
                if (MODE == 0) {
                    Cb[(size_t)row * N + col] = f2bf(val);
                } else {
                    size_t idx = (size_t)row * N + col;
                    Cf[idx] = resid[idx] + val;
                }
            }
        }
    }
}

// ---------------- windowed block attention (band-limited) ----------------
// grid: B*H*NB blocks; 256 threads = 4 waves x 32 query rows.
// Per m-frag (16 queries at frag index m0 = 2w+mf), only key frags m0..m0+8 are unmasked.
// LDS: [0,32768) K [256 keys][64 dh] XOR-swizzled (reused as Vt [64][264] swizzled after QK^T);
//      [33792, 44032) per-wave P staging [32][40].
__global__ __launch_bounds__(256, 3) void attn_kernel(const unsigned short* __restrict__ qkv,
                                                      unsigned short* __restrict__ obuf) {
    constexpr int S = 4096, D = 1024, H = 16, W = 128, NB = 32;
    constexpr int TD = 3 * D;
    constexpr int PS = 40;

    __shared__ __align__(16) char smem[44032];
    unsigned short* KV = (unsigned short*)smem;

    int bid = blockIdx.x;
    int blk = bid % NB;
    int h = (bid / NB) % H;
    int b = bid / (NB * H);

    int tid = threadIdx.x, lane = tid & 63, w = tid >> 6;
    int hl = lane >> 4, ll = lane & 15;
    unsigned short* Ps = (unsigned short*)(smem + 33792) + w * 32 * PS;

    int kbase = blk * W - W;            // global s of extended key 0
    size_t rowbase = (size_t)(b * S);

    // ---- stage K [256][64] via async global_load_lds, source pre-swizzled ----
    {
        int lr = lane >> 3;                       // row within 8-row chunk
        int scb = ((lane & 7) ^ lr) * 16;         // swizzled source byte col
#pragma unroll
        for (int r = 0; r < 8; r++) {
            int row = r * 32 + w * 8 + lr;        // ext key index
            int s = kbase + row;
            s = s < 0 ? 0 : s;                    // clamp (blk 0: masked later, finite data)
            const char* src = (const char*)(qkv + (rowbase + s) * TD + D + h * 64) + scb;
            char* dst = smem + (size_t)(r * 32 + w * 8) * 128 + lane * 16;
            gload_lds16(src, dst);
        }
    }

    // ---- Q fragments ----
    s8v qf[2][2];
    {
        const unsigned short* qb = qkv + (rowbase + blk * W + w * 32) * TD + h * 64;
#pragma unroll
        for (int mf = 0; mf < 2; mf++)
#pragma unroll
            for (int ks = 0; ks < 2; ks++)
                qf[mf][ks] = *(const s8v*)(qb + (size_t)(mf * 16 + ll) * TD + ks * 32 + hl * 8);
    }

    // ---- prefetch V into regs: lane owns 8x8 block V[k0..k0+7][d0..d0+7] ----
    s8v vreg[8];
    {
        int k0 = w * 64 + (lane >> 3) * 8;
        int d0 = (lane & 7) * 8;
#pragma unroll
        for (int it = 0; it < 8; it++) {
            int s = kbase + k0 + it;
            s = s < 0 ? 0 : s;
            vreg[it] = *(const s8v*)(qkv + (rowbase + s) * TD + 2 * D + h * 64 + d0);
        }
    }
    __syncthreads();   // K in LDS (V regs also arrived)

    // ---- QK^T: band of 9 key frags per m-frag; kf shared across mf via 10-frag sweep ----
    f4v sc[2][9] = {};
    int g0 = w * 2;
    __builtin_amdgcn_s_setprio(1);
#pragma unroll
    for (int gi = 0; gi < 10; gi++) {
#pragma unroll
        for (int ks = 0; ks < 2; ks++) {
            int row = (g0 + gi) * 16 + ll;
            s8v kf = *(const s8v*)(smem + (size_t)row * 128 +
                                   (((unsigned)(ks * 64 + hl * 16)) ^ ((ll & 7) << 4)));
            if (gi < 9) sc[0][gi] = MFMA_BF16(qf[0][ks], kf, sc[0][gi]);
            if (gi > 0) sc[1][gi - 1] = MFMA_BF16(qf[1][ks], kf, sc[1][gi - 1]);
        }
    }
    __builtin_amdgcn_s_setprio(0);

    // ---- mask + scale + softmax (rows across 16 lanes of quarter-wave) ----
    float linv[2][4];
#pragma unroll
    for (int mf = 0; mf < 2; mf++) {
#pragma unroll
        for (int r = 0; r < 4; r++) {
            int ip = hl * 4 + r;                  // query pos within m-frag
            float mx = -1e30f;
#pragma unroll
            for (int nf = 0; nf < 9; nf++) {
                bool ok = (nf > 0 || ll > ip) && (nf < 8 || ll <= ip) &&
                          (blk > 0 || (g0 + mf + nf) >= 8);
                float sval = ok ? sc[mf][nf][r] * 0.125f : -1e30f;
                sc[mf][nf][r] = sval;
                mx = fmaxf(mx, sval);
            }
#pragma unroll
            for (int off = 1; off < 16; off <<= 1) mx = fmaxf(mx, __shfl_xor(mx, off, 64));
            float sum = 0.f;
#pragma unroll
            for (int nf = 0; nf < 9; nf++) {
                float p = __expf(sc[mf][nf][r] - mx);
                sc[mf][nf][r] = p;
                sum += p;
            }
#pragma unroll
            for (int off = 1; off < 16; off <<= 1) sum += __shfl_xor(sum, off, 64);
            linv[mf][r] = 1.f / sum;
        }
    }

    __syncthreads();   // all waves done reading K

    // ---- write V transposed: in-register 8x8 transpose, 8 x ds_write_b128 ----
    // Vt[d][k'] with k' = k ^ (((d>>3)&7)<<3); read side applies the same XOR.
    {
        int k0 = w * 64 + (lane >> 3) * 8;
        int d0 = (lane & 7) * 8;
#pragma unroll
        for (int e = 0; e < 8; e++) {
            int d = d0 + e;
            s8v tmp;
#pragma unroll
            for (int i = 0; i < 8; i++) tmp[i] = vreg[i][e];
            *(s8v*)(KV + d * 264 + (k0 ^ (((d >> 3) & 7) << 3))) = tmp;
        }
    }
    __syncthreads();   // Vt visible

    // ---- PV: 5 chunks of 32 keys starting at wave base w*32 ----
    f4v o[2][4] = {};
#pragma unroll
    for (int c = 0; c < 5; c++) {
#pragma unroll
        for (int mf = 0; mf < 2; mf++) {
#pragma unroll
            for (int j16 = 0; j16 < 2; j16++) {
                int nf = c * 2 + j16 - mf;
                int nfc = nf < 0 ? 0 : (nf > 8 ? 8 : nf);
#pragma unroll
                for (int r = 0; r < 4; r++) {
                    float val = (nf >= 0 && nf < 9) ? sc[mf][nfc][r] : 0.f;
                    Ps[(mf * 16 + hl * 4 + r) * PS + j16 * 16 + ll] = f2bf(val);
                }
            }
        }
        asm volatile("s_waitcnt lgkmcnt(0)" ::: "memory");
        s8v pa[2];
        pa[0] = *(const s8v*)(Ps + ll * PS + hl * 8);
        pa[1] = *(const s8v*)(Ps + (16 + ll) * PS + hl * 8);
        int cb = (w + c) * 32;
        __builtin_amdgcn_s_setprio(1);
#pragma unroll
        for (int nd = 0; nd < 4; nd++) {
            int d = nd * 16 + ll;
            int kk = (cb + hl * 8) ^ (((d >> 3) & 7) << 3);
            s8v vb = *(const s8v*)(KV + d * 264 + kk);
            o[0][nd] = MFMA_BF16(pa[0], vb, o[0][nd]);
            o[1][nd] = MFMA_BF16(pa[1], vb, o[1][nd]);
        }
        __builtin_amdgcn_s_setprio(0);
    }

    // ---- write O (bf16) ----
    unsigned short* ob = obuf + (rowbase + blk * W + w * 32) * D + h * 64;
#pragma unroll
    for (int mf = 0; mf < 2; mf++)
#pragma unroll
        for (int r = 0; r < 4; r++) {
            int row = mf * 16 + hl * 4 + r;
#pragma unroll
            for (int nd = 0; nd < 4; nd++)
                ob[(size_t)row * D + nd * 16 + ll] = f2bf(o[mf][nd][r] * linv[mf][r]);
        }
}

// ---------------- launch ----------------
extern "C" void kernel_launch(void* const* d_in, const int* in_sizes, int n_in,
                              void* d_out, int out_size, void* d_ws, size_t ws_size,
                              hipStream_t stream) {
    const float* x = (const float*)d_in[0];
    const float* g = (const float*)d_in[1];
    const float* Wqkv = (const float*)d_in[2];
    const float* Wo = (const float*)d_in[3];
    float* out = (float*)d_out;

    const int S = 4096, D = 1024, B = 4;
    const int M = B * S;  // 16384
    const int N3 = 3 * D; // 3072

    // workspace layout (bytes):
    //   [0, 6291456)            WqkvT bf16 [3072][1024]
    //   [6291456, 8388608)      WoT   bf16 [1024][1024]
    //   [8388608, 41943040)     xn    bf16 [16384][1024]  (reused as attention output)
    //   [41943040, 142606336)   qkv   bf16 [16384][3072]
    char* ws = (char*)d_ws;
    unsigned short* WqkvT = (unsigned short*)ws;
    unsigned short* WoT = (unsigned short*)(ws + 6291456);
    unsigned short* xn = (unsigned short*)(ws + 8388608);
    unsigned short* qkv = (unsigned short*)(ws + 41943040);

    transpose_cast_kernel<<<dim3((D / 32) * (N3 / 32) + (D / 32) * (D / 32)), dim3(256), 0,
                            stream>>>(Wqkv, WqkvT, Wo, WoT);
    rmsnorm_kernel<<<dim3(M), dim3(256), 0, stream>>>(x, g, xn);
    gemm256_kernel<0><<<dim3((M / 256) * (N3 / 256)), dim3(512), 0, stream>>>(
        xn, WqkvT, qkv, nullptr, nullptr, M, N3, D);
    attn_kernel<<<dim3(B * 16 * (S / 128)), dim3(256), 0, stream>>>(qkv, xn);
    gemm256_kernel<1><<<dim3((M / 256) * (D / 256)), dim3(512), 0, stream>>>(
        xn, WoT, nullptr, out, x, M, D, D);
}

// Round 9
// 220.740 us; speedup vs baseline: 1.7721x; 1.7721x over previous
//
#include <hip/hip_runtime.h>
#include <hip/hip_bf16.h>

// TelephoneAttentionBlock: x[4,4096,1024] fp32 -> RMSNorm -> QKV (bf16 MFMA GEMM)
// -> windowed block attention (16 heads, dh=64, window 128) -> Wo GEMM + residual -> fp32 out.
// Round 9: GEMM restored to R5-proven 8-phase (R8's B-direct died of in-order vmcnt
// retire: waiting on B forced waiting on the newer... older A-stage -> full serialization).
// Attention: 2 consecutive seq-blocks per workgroup (512 thr, 2 groups x 4 waves) sharing
// one 384-key K/V stage -> K/V HBM -25%, blocks 2048->1024.

typedef __attribute__((ext_vector_type(8))) short s8v;   // 8 bf16 (4 VGPRs)
typedef __attribute__((ext_vector_type(4))) float f4v;   // MFMA accumulator

#define MFMA_BF16(A, B, C) __builtin_amdgcn_mfma_f32_16x16x32_bf16((A), (B), (C), 0, 0, 0)

static __device__ __forceinline__ void gload_lds16(const void* g, void* l) {
    // async global->LDS, 16B per lane; LDS dest = wave-uniform base + lane*16
    __builtin_amdgcn_global_load_lds((const __attribute__((address_space(1))) void*)g,
                                     (__attribute__((address_space(3))) void*)l, 16, 0, 0);
}

static __device__ __forceinline__ unsigned short f2bf(float f) {
    return __builtin_bit_cast(unsigned short, __float2bfloat16(f));
}

// ---------------- weight cast + transpose (both weights in one launch) ----------------
__global__ __launch_bounds__(256) void transpose_cast_kernel(const float* __restrict__ Wqkv,
                                                             unsigned short* __restrict__ WqkvT,
                                                             const float* __restrict__ Wo,
                                                             unsigned short* __restrict__ WoT) {
    const int K = 1024;
    int nb1 = (K >> 5) * (3072 >> 5);
    const float* in;
    unsigned short* out;
    int N, bidx;
    if (blockIdx.x < (unsigned)nb1) {
        in = Wqkv; out = WqkvT; N = 3072; bidx = blockIdx.x;
    } else {
        in = Wo; out = WoT; N = 1024; bidx = blockIdx.x - nb1;
    }
    __shared__ float tile[32][33];
    int nbk = K >> 5;
    int bk = bidx % nbk;
    int bn = bidx / nbk;
    int tx = threadIdx.x & 31, ty = threadIdx.x >> 5;
#pragma unroll
    for (int i = 0; i < 4; i++) {
        int r = ty + i * 8;
        tile[r][tx] = in[(size_t)(bk * 32 + r) * N + bn * 32 + tx];
    }
    __syncthreads();
#pragma unroll
    for (int i = 0; i < 4; i++) {
        int r = ty + i * 8;
        out[(size_t)(bn * 32 + r) * K + bk * 32 + tx] = f2bf(tile[tx][r]);
    }
}

// ---------------- RMSNorm: x fp32 [M][1024] -> xn bf16 ----------------
__global__ __launch_bounds__(256) void rmsnorm_kernel(const float* __restrict__ x,
                                                      const float* __restrict__ g,
                                                      unsigned short* __restrict__ xn) {
    const int D = 1024;
    int row = blockIdx.x;
    int t = threadIdx.x;
    float4 v = ((const float4*)(x + (size_t)row * D))[t];
    float ss = v.x * v.x + v.y * v.y + v.z * v.z + v.w * v.w;
#pragma unroll
    for (int off = 32; off >= 1; off >>= 1) ss += __shfl_xor(ss, off, 64);
    __shared__ float partials[4];
    if ((t & 63) == 0) partials[t >> 6] = ss;
    __syncthreads();
    float tot = partials[0] + partials[1] + partials[2] + partials[3];
    float scale = rsqrtf(tot * (1.0f / D) + 1e-6f);
    float4 gv = ((const float4*)g)[t];
    ushort4 o;
    o.x = f2bf(v.x * scale * gv.x);
    o.y = f2bf(v.y * scale * gv.y);
    o.z = f2bf(v.z * scale * gv.z);
    o.w = f2bf(v.w * scale * gv.w);
    ((ushort4*)xn)[(size_t)row * (D / 4) + t] = o;
}

// ---------------- GEMM 256x256, BK=64, 8-phase counted-vmcnt (R5 proven) ----------------
template <int MODE>
__global__ __launch_bounds__(512, 2) void gemm256_kernel(const unsigned short* __restrict__ A,
                                                         const unsigned short* __restrict__ Bt,
                                                         unsigned short* __restrict__ Cb,
                                                         float* __restrict__ Cf,
                                                         const float* __restrict__ resid,
                                                         int M, int N, int K) {
    __shared__ __align__(16) char lds_s[131072];

    const int nbn = N >> 8;
    const int nwg = (M >> 8) * nbn;
    int bid = blockIdx.x;
    int cpx = nwg >> 3;
    int wg = (bid & 7) * cpx + (bid >> 3);
    int bm = wg / nbn, bn = wg % nbn;

    int tid = threadIdx.x, lane = tid & 63, w = tid >> 6;
    int wm = w >> 2, wn = w & 3;
    int hl = lane >> 4, ll = lane & 15;

    const unsigned short* Ab = A + (size_t)bm * 256 * K;
    const unsigned short* Bb = Bt + (size_t)bn * 256 * K;

    int srow = lane >> 3;
    int scol = ((lane & 7) ^ srow) * 8;

    int c0 = (hl * 16) ^ ((ll & 7) * 16);
    const char* ldsA0 = lds_s + wm * 16384 + ll * 128 + c0;
    const char* ldsA1 = lds_s + wm * 16384 + ll * 128 + (c0 ^ 64);
    const char* ldsB0 = lds_s + 32768 + (wn >> 1) * 16384 + ((wn & 1) * 64 + ll) * 128 + c0;
    const char* ldsB1 = lds_s + 32768 + (wn >> 1) * 16384 + ((wn & 1) * 64 + ll) * 128 + (c0 ^ 64);

    const int NT = K >> 6;

    f4v acc[8][4] = {};
    s8v bfr[4][2];

#define STAGE(t_, isB_, h_) do {                                                          \
        int te_ = (t_) < NT ? (t_) : (t_)-NT;                                             \
        const unsigned short* g_ = ((isB_) ? Bb : Ab)                                     \
            + (size_t)((h_)*128 + srow) * K + te_ * 64 + scol;                            \
        char* l_ = lds_s + (((t_)&1) * 65536 + (isB_)*32768 + (h_)*16384);                \
        gload_lds16(g_ + (size_t)(w * 8) * K, l_ + w * 1024);                             \
        gload_lds16(g_ + (size_t)(64 + w * 8) * K, l_ + 8192 + w * 1024);                 \
    } while (0)

#define PHASE(buf_, p4_, st_, sb_, sh_, dv_) do {                                         \
        s8v a0k0 = *(const s8v*)(ldsA0 + (buf_)*65536 + (2 * (p4_)) * 2048);              \
        s8v a0k1 = *(const s8v*)(ldsA1 + (buf_)*65536 + (2 * (p4_)) * 2048);              \
        s8v a1k0 = *(const s8v*)(ldsA0 + (buf_)*65536 + (2 * (p4_) + 1) * 2048);          \
        s8v a1k1 = *(const s8v*)(ldsA1 + (buf_)*65536 + (2 * (p4_) + 1) * 2048);          \
        if ((p4_) == 0) {                                                                 \
            _Pragma("unroll") for (int n = 0; n < 4; n++) {                               \
                bfr[n][0] = *(const s8v*)(ldsB0 + (buf_)*65536 + n * 2048);               \
                bfr[n][1] = *(const s8v*)(ldsB1 + (buf_)*65536 + n * 2048);               \
            }                                                                             \
        }                                                                                 \
        STAGE(st_, sb_, sh_);                                                             \
        if (dv_) asm volatile("s_waitcnt vmcnt(4)" ::: "memory");                         \
        asm volatile("s_barrier" ::: "memory");                                           \
        asm volatile("s_waitcnt lgkmcnt(0)" ::: "memory");                                \
        __builtin_amdgcn_s_setprio(1);                                                    \
        _Pragma("unroll") for (int n = 0; n < 4; n++) {                                   \
            acc[2 * (p4_)][n] = MFMA_BF16(a0k0, bfr[n][0], acc[2 * (p4_)][n]);            \
            acc[2 * (p4_)][n] = MFMA_BF16(a0k1, bfr[n][1], acc[2 * (p4_)][n]);            \
            acc[2 * (p4_) + 1][n] = MFMA_BF16(a1k0, bfr[n][0], acc[2 * (p4_) + 1][n]);    \
            acc[2 * (p4_) + 1][n] = MFMA_BF16(a1k1, bfr[n][1], acc[2 * (p4_) + 1][n]);    \
        }                                                                                 \
        __builtin_amdgcn_s_setprio(0);                                                    \
        asm volatile("s_barrier" ::: "memory");                                           \
    } while (0)

    STAGE(0, 0, 0); STAGE(0, 0, 1); STAGE(0, 1, 0); STAGE(0, 1, 1);
    STAGE(1, 1, 0); STAGE(1, 1, 1);
    asm volatile("s_waitcnt vmcnt(4)" ::: "memory");
    asm volatile("s_barrier" ::: "memory");

    for (int i = 0; i < NT / 2; i++) {
        int t1 = 2 * i + 1;
        PHASE(0, 0, t1, 0, 0, 0);
        PHASE(0, 1, t1, 0, 1, 0);
        PHASE(0, 2, t1 + 1, 1, 0, 0);
        PHASE(0, 3, t1 + 1, 1, 1, 1);
        PHASE(1, 0, t1 + 1, 0, 0, 0);
        PHASE(1, 1, t1 + 1, 0, 1, 0);
        PHASE(1, 2, t1 + 2, 1, 0, 0);
        PHASE(1, 3, t1 + 2, 1, 1, 1);
    }
#undef PHASE
#undef STAGE

    int crow0 = bm * 256 + wm * 128;
    int ccol0 = bn * 256 + wn * 64;
#pragma unroll
    for (int m = 0; m < 8; m++) {
#pragma unroll
        for (int r = 0; r < 4; r++) {
            int row = crow0 + m * 16 + hl * 4 + r;
#pragma unroll
            for (int n = 0; n < 4; n++) {
                int col = ccol0 + n * 16 + ll;
                float val = acc[m][n][r];
                if (MODE == 0) {
                    Cb[(size_t)row * N + col] = f2bf(val);
                } else {
                    size_t idx = (size_t)row * N + col;
                    Cf[idx] = resid[idx] + val;
                }
            }
        }
    }
}

// ---------------- windowed block attention: 2 seq-blocks per workgroup ----------------
// grid: B*H*(NB/2) = 1024 blocks; 512 threads = 2 groups (g) x 4 waves (wl); each group
// handles one 128-query block. Shared K/V stage spans 384 keys [blkpair*2*W - W, +384).
// Group g's 256-key window = LDS offset g*128. Band mask identical per group.
// LDS: [0,49152) K [384][64] XOR-swizzled (reused as Vt [64][392] after QK^T);
//      [51200, 71680) per-wave P staging [32][40].
__global__ __launch_bounds__(512, 2) void attn_kernel(const unsigned short* __restrict__ qkv,
                                                      unsigned short* __restrict__ obuf) {
    constexpr int S = 4096, D = 1024, H = 16, W = 128, NP = 16;
    constexpr int TD = 3 * D;
    constexpr int PS = 40, VS = 392;

    __shared__ __align__(16) char smem[71680];
    unsigned short* KV = (unsigned short*)smem;

    int bid = blockIdx.x;
    int bp = bid % NP;
    int h = (bid / NP) % H;
    int b = bid / (NP * H);

    int tid = threadIdx.x, lane = tid & 63, w = tid >> 6;
    int g = w >> 2, wl = w & 3;          // group, wave-within-group
    int hl = lane >> 4, ll = lane & 15;
    unsigned short* Ps = (unsigned short*)(smem + 51200) + w * 32 * PS;

    int kb0 = bp * 2 * W - W;            // global s of staged key 0 (-128 for bp=0)
    int blk_g = bp * 2 + g;              // this group's query block
    size_t rowbase = (size_t)(b * S);

    // ---- stage K [384][64] via async global_load_lds, source pre-swizzled; 6 rounds ----
    {
        int lr = lane >> 3;
        int scb = ((lane & 7) ^ lr) * 16;
#pragma unroll
        for (int r = 0; r < 6; r++) {
            int row = r * 64 + w * 8 + lr;
            int s = kb0 + row;
            s = s < 0 ? 0 : s;           // clamp (bp 0, g 0: masked later)
            const char* src = (const char*)(qkv + (rowbase + s) * TD + D + h * 64) + scb;
            char* dst = smem + (size_t)(r * 64 + w * 8) * 128 + lane * 16;
            gload_lds16(src, dst);
        }
    }

    // ---- Q fragments (group's own 32-row slice) ----
    s8v qf[2][2];
    {
        const unsigned short* qb = qkv + (rowbase + blk_g * W + wl * 32) * TD + h * 64;
#pragma unroll
        for (int mf = 0; mf < 2; mf++)
#pragma unroll
            for (int ks = 0; ks < 2; ks++)
                qf[mf][ks] = *(const s8v*)(qb + (size_t)(mf * 16 + ll) * TD + ks * 32 + hl * 8);
    }

    // ---- prefetch V into regs: thread (tid<384) owns 8x8 block V[k0..+8)[d0..+8) ----
    s8v vreg[8];
    int vkblk = tid >> 3;                // 0..63; only <48 active
    int vd0 = (tid & 7) * 8;
    if (vkblk < 48) {
        int k0 = vkblk * 8;
#pragma unroll
        for (int it = 0; it < 8; it++) {
            int s = kb0 + k0 + it;
            s = s < 0 ? 0 : s;
            vreg[it] = *(const s8v*)(qkv + (rowbase + s) * TD + 2 * D + h * 64 + vd0);
        }
    }
    __syncthreads();   // K in LDS

    // ---- QK^T: band of 9 key frags per m-frag within group's 256-key window ----
    f4v sc[2][9] = {};
    int g0 = wl * 2;
    __builtin_amdgcn_s_setprio(1);
#pragma unroll
    for (int gi = 0; gi < 10; gi++) {
#pragma unroll
        for (int ks = 0; ks < 2; ks++) {
            int row = g * 128 + (g0 + gi) * 16 + ll;
            s8v kf = *(const s8v*)(smem + (size_t)row * 128 +
                                   (((unsigned)(ks * 64 + hl * 16)) ^ ((ll & 7) << 4)));
            if (gi < 9) sc[0][gi] = MFMA_BF16(qf[0][ks], kf, sc[0][gi]);
            if (gi > 0) sc[1][gi - 1] = MFMA_BF16(qf[1][ks], kf, sc[1][gi - 1]);
        }
    }
    __builtin_amdgcn_s_setprio(0);

    // ---- mask + scale + softmax ----
    float linv[2][4];
#pragma unroll
    for (int mf = 0; mf < 2; mf++) {
#pragma unroll
        for (int r = 0; r < 4; r++) {
            int ip = hl * 4 + r;
            float mx = -1e30f;
#pragma unroll
            for (int nf = 0; nf < 9; nf++) {
                bool ok = (nf > 0 || ll > ip) && (nf < 8 || ll <= ip) &&
                          (blk_g > 0 || (g0 + mf + nf) >= 8);
                float sval = ok ? sc[mf][nf][r] * 0.125f : -1e30f;
                sc[mf][nf][r] = sval;
                mx = fmaxf(mx, sval);
            }
#pragma unroll
            for (int off = 1; off < 16; off <<= 1) mx = fmaxf(mx, __shfl_xor(mx, off, 64));
            float sum = 0.f;
#pragma unroll
            for (int nf = 0; nf < 9; nf++) {
                float p = __expf(sc[mf][nf][r] - mx);
                sc[mf][nf][r] = p;
                sum += p;
            }
#pragma unroll
            for (int off = 1; off < 16; off <<= 1) sum += __shfl_xor(sum, off, 64);
            linv[mf][r] = 1.f / sum;
        }
    }

    __syncthreads();   // all waves done reading K

    // ---- write V transposed: 8x8 in-register transpose, 8 x ds_write_b128 ----
    // Vt[d][k'] with k' = k ^ (((d>>3)&7)<<3)
    if (vkblk < 48) {
        int k0 = vkblk * 8;
#pragma unroll
        for (int e = 0; e < 8; e++) {
            int d = vd0 + e;
            s8v tmp;
#pragma unroll
            for (int i = 0; i < 8; i++) tmp[i] = vreg[i][e];
            *(s8v*)(KV + d * VS + (k0 ^ (((d >> 3) & 7) << 3))) = tmp;
        }
    }
    __syncthreads();   // Vt visible

    // ---- PV: 5 chunks of 32 keys starting at window base g*128 + wl*32 ----
    f4v o[2][4] = {};
#pragma unroll
    for (int c = 0; c < 5; c++) {
#pragma unroll
        for (int mf = 0; mf < 2; mf++) {
#pragma unroll
            for (int j16 = 0; j16 < 2; j16++) {
                int nf = c * 2 + j16 - mf;
                int nfc = nf < 0 ? 0 : (nf > 8 ? 8 : nf);
#pragma unroll
                for (int r = 0; r < 4; r++) {
                    float val = (nf >= 0 && nf < 9) ? sc[mf][nfc][r] : 0.f;
                    Ps[(mf * 16 + hl * 4 + r) * PS + j16 * 16 + ll] = f2bf(val);
                }
            }
        }
        asm volatile("s_waitcnt lgkmcnt(0)" ::: "memory");
        s8v pa[2];
        pa[0] = *(const s8v*)(Ps + ll * PS + hl * 8);
        pa[1] = *(const s8v*)(Ps + (16 + ll) * PS + hl * 8);
        int cb = g * 128 + (wl + c) * 32;
        __builtin_amdgcn_s_setprio(1);
#pragma unroll
        for (int nd = 0; nd < 4; nd++) {
            int d = nd * 16 + ll;
            int kk = (cb + hl * 8) ^ (((d >> 3) & 7) << 3);
            s8v vb = *(const s8v*)(KV + d * VS + kk);
            o[0][nd] = MFMA_BF16(pa[0], vb, o[0][nd]);
            o[1][nd] = MFMA_BF16(pa[1], vb, o[1][nd]);
        }
        __builtin_amdgcn_s_setprio(0);
    }

    // ---- write O (bf16) ----
    unsigned short* ob = obuf + (rowbase + blk_g * W + wl * 32) * D + h * 64;
#pragma unroll
    for (int mf = 0; mf < 2; mf++)
#pragma unroll
        for (int r = 0; r < 4; r++) {
            int row = mf * 16 + hl * 4 + r;
#pragma unroll
            for (int nd = 0; nd < 4; nd++)
                ob[(size_t)row * D + nd * 16 + ll] = f2bf(o[mf][nd][r] * linv[mf][r]);
        }
}

// ---------------- launch ----------------
extern "C" void kernel_launch(void* const* d_in, const int* in_sizes, int n_in,
                              void* d_out, int out_size, void* d_ws, size_t ws_size,
                              hipStream_t stream) {
    const float* x = (const float*)d_in[0];
    const float* g = (const float*)d_in[1];
    const float* Wqkv = (const float*)d_in[2];
    const float* Wo = (const float*)d_in[3];
    float* out = (float*)d_out;

    const int S = 4096, D = 1024, B = 4;
    const int M = B * S;  // 16384
    const int N3 = 3 * D; // 3072

    // workspace layout (bytes):
    //   [0, 6291456)            WqkvT bf16 [3072][1024]
    //   [6291456, 8388608)      WoT   bf16 [1024][1024]
    //   [8388608, 41943040)     xn    bf16 [16384][1024]  (reused as attention output)
    //   [41943040, 142606336)   qkv   bf16 [16384][3072]
    char* ws = (char*)d_ws;
    unsigned short* WqkvT = (unsigned short*)ws;
    unsigned short* WoT = (unsigned short*)(ws + 6291456);
    unsigned short* xn = (unsigned short*)(ws + 8388608);
    unsigned short* qkv = (unsigned short*)(ws + 41943040);

    transpose_cast_kernel<<<dim3((D / 32) * (N3 / 32) + (D / 32) * (D / 32)), dim3(256), 0,
                            stream>>>(Wqkv, WqkvT, Wo, WoT);
    rmsnorm_kernel<<<dim3(M), dim3(256), 0, stream>>>(x, g, xn);
    gemm256_kernel<0><<<dim3((M / 256) * (N3 / 256)), dim3(512), 0, stream>>>(
        xn, WqkvT, qkv, nullptr, nullptr, M, N3, D);
    attn_kernel<<<dim3(B * 16 * (S / 128 / 2)), dim3(512), 0, stream>>>(qkv, xn);
    gemm256_kernel<1><<<dim3((M / 256) * (D / 256)), dim3(512), 0, stream>>>(
        xn, WoT, nullptr, out, x, M, D, D);
}

// Round 10
// 207.727 us; speedup vs baseline: 1.8832x; 1.0626x over previous
//
#include <hip/hip_runtime.h>
#include <hip/hip_bf16.h>

// TelephoneAttentionBlock: x[4,4096,1024] fp32 -> RMSNorm -> QKV (bf16 MFMA GEMM)
// -> windowed block attention (16 heads, dh=64, window 128) -> Wo GEMM + residual -> fp32 out.
// Round 10: best-known composite. GEMM = R5 8-phase 256^2 (971 TF plateau);
// attn = R5 256-thread band-9 kernel (R9's 2-block merge regressed: 1 block/CU,
// wider barrier domain); weight transposes fused into one launch (R8's good piece).

typedef __attribute__((ext_vector_type(8))) short s8v;   // 8 bf16 (4 VGPRs)
typedef __attribute__((ext_vector_type(4))) float f4v;   // MFMA accumulator

#define MFMA_BF16(A, B, C) __builtin_amdgcn_mfma_f32_16x16x32_bf16((A), (B), (C), 0, 0, 0)

static __device__ __forceinline__ void gload_lds16(const void* g, void* l) {
    // async global->LDS, 16B per lane; LDS dest = wave-uniform base + lane*16
    __builtin_amdgcn_global_load_lds((const __attribute__((address_space(1))) void*)g,
                                     (__attribute__((address_space(3))) void*)l, 16, 0, 0);
}

static __device__ __forceinline__ unsigned short f2bf(float f) {
    return __builtin_bit_cast(unsigned short, __float2bfloat16(f));
}

// ---------------- weight cast + transpose (both weights in one launch) ----------------
__global__ __launch_bounds__(256) void transpose_cast_kernel(const float* __restrict__ Wqkv,
                                                             unsigned short* __restrict__ WqkvT,
                                                             const float* __restrict__ Wo,
                                                             unsigned short* __restrict__ WoT) {
    const int K = 1024;
    int nb1 = (K >> 5) * (3072 >> 5);
    const float* in;
    unsigned short* out;
    int N, bidx;
    if (blockIdx.x < (unsigned)nb1) {
        in = Wqkv; out = WqkvT; N = 3072; bidx = blockIdx.x;
    } else {
        in = Wo; out = WoT; N = 1024; bidx = blockIdx.x - nb1;
    }
    __shared__ float tile[32][33];
    int nbk = K >> 5;
    int bk = bidx % nbk;
    int bn = bidx / nbk;
    int tx = threadIdx.x & 31, ty = threadIdx.x >> 5;
#pragma unroll
    for (int i = 0; i < 4; i++) {
        int r = ty + i * 8;
        tile[r][tx] = in[(size_t)(bk * 32 + r) * N + bn * 32 + tx];
    }
    __syncthreads();
#pragma unroll
    for (int i = 0; i < 4; i++) {
        int r = ty + i * 8;
        out[(size_t)(bn * 32 + r) * K + bk * 32 + tx] = f2bf(tile[tx][r]);
    }
}

// ---------------- RMSNorm: x fp32 [M][1024] -> xn bf16 ----------------
__global__ __launch_bounds__(256) void rmsnorm_kernel(const float* __restrict__ x,
                                                      const float* __restrict__ g,
                                                      unsigned short* __restrict__ xn) {
    const int D = 1024;
    int row = blockIdx.x;
    int t = threadIdx.x;
    float4 v = ((const float4*)(x + (size_t)row * D))[t];
    float ss = v.x * v.x + v.y * v.y + v.z * v.z + v.w * v.w;
#pragma unroll
    for (int off = 32; off >= 1; off >>= 1) ss += __shfl_xor(ss, off, 64);
    __shared__ float partials[4];
    if ((t & 63) == 0) partials[t >> 6] = ss;
    __syncthreads();
    float tot = partials[0] + partials[1] + partials[2] + partials[3];
    float scale = rsqrtf(tot * (1.0f / D) + 1e-6f);
    float4 gv = ((const float4*)g)[t];
    ushort4 o;
    o.x = f2bf(v.x * scale * gv.x);
    o.y = f2bf(v.y * scale * gv.y);
    o.z = f2bf(v.z * scale * gv.z);
    o.w = f2bf(v.w * scale * gv.w);
    ((ushort4*)xn)[(size_t)row * (D / 4) + t] = o;
}

// ---------------- GEMM 256x256, BK=64, 8-phase counted-vmcnt (R5 proven) ----------------
template <int MODE>
__global__ __launch_bounds__(512, 2) void gemm256_kernel(const unsigned short* __restrict__ A,
                                                         const unsigned short* __restrict__ Bt,
                                                         unsigned short* __restrict__ Cb,
                                                         float* __restrict__ Cf,
                                                         const float* __restrict__ resid,
                                                         int M, int N, int K) {
    __shared__ __align__(16) char lds_s[131072];

    const int nbn = N >> 8;
    const int nwg = (M >> 8) * nbn;
    int bid = blockIdx.x;
    int cpx = nwg >> 3;
    int wg = (bid & 7) * cpx + (bid >> 3);
    int bm = wg / nbn, bn = wg % nbn;

    int tid = threadIdx.x, lane = tid & 63, w = tid >> 6;
    int wm = w >> 2, wn = w & 3;
    int hl = lane >> 4, ll = lane & 15;

    const unsigned short* Ab = A + (size_t)bm * 256 * K;
    const unsigned short* Bb = Bt + (size_t)bn * 256 * K;

    int srow = lane >> 3;
    int scol = ((lane & 7) ^ srow) * 8;

    int c0 = (hl * 16) ^ ((ll & 7) * 16);
    const char* ldsA0 = lds_s + wm * 16384 + ll * 128 + c0;
    const char* ldsA1 = lds_s + wm * 16384 + ll * 128 + (c0 ^ 64);
    const char* ldsB0 = lds_s + 32768 + (wn >> 1) * 16384 + ((wn & 1) * 64 + ll) * 128 + c0;
    const char* ldsB1 = lds_s + 32768 + (wn >> 1) * 16384 + ((wn & 1) * 64 + ll) * 128 + (c0 ^ 64);

    const int NT = K >> 6;

    f4v acc[8][4] = {};
    s8v bfr[4][2];

#define STAGE(t_, isB_, h_) do {                                                          \
        int te_ = (t_) < NT ? (t_) : (t_)-NT;                                             \
        const unsigned short* g_ = ((isB_) ? Bb : Ab)                                     \
            + (size_t)((h_)*128 + srow) * K + te_ * 64 + scol;                            \
        char* l_ = lds_s + (((t_)&1) * 65536 + (isB_)*32768 + (h_)*16384);                \
        gload_lds16(g_ + (size_t)(w * 8) * K, l_ + w * 1024);                             \
        gload_lds16(g_ + (size_t)(64 + w * 8) * K, l_ + 8192 + w * 1024);                 \
    } while (0)

#define PHASE(buf_, p4_, st_, sb_, sh_, dv_) do {                                         \
        s8v a0k0 = *(const s8v*)(ldsA0 + (buf_)*65536 + (2 * (p4_)) * 2048);              \
        s8v a0k1 = *(const s8v*)(ldsA1 + (buf_)*65536 + (2 * (p4_)) * 2048);              \
        s8v a1k0 = *(const s8v*)(ldsA0 + (buf_)*65536 + (2 * (p4_) + 1) * 2048);          \
        s8v a1k1 = *(const s8v*)(ldsA1 + (buf_)*65536 + (2 * (p4_) + 1) * 2048);          \
        if ((p4_) == 0) {                                                                 \
            _Pragma("unroll") for (int n = 0; n < 4; n++) {                               \
                bfr[n][0] = *(const s8v*)(ldsB0 + (buf_)*65536 + n * 2048);               \
                bfr[n][1] = *(const s8v*)(ldsB1 + (buf_)*65536 + n * 2048);               \
            }                                                                             \
        }                                                                                 \
        STAGE(st_, sb_, sh_);                                                             \
        if (dv_) asm volatile("s_waitcnt vmcnt(4)" ::: "memory");                         \
        asm volatile("s_barrier" ::: "memory");                                           \
        asm volatile("s_waitcnt lgkmcnt(0)" ::: "memory");                                \
        __builtin_amdgcn_s_setprio(1);                                                    \
        _Pragma("unroll") for (int n = 0; n < 4; n++) {                                   \
            acc[2 * (p4_)][n] = MFMA_BF16(a0k0, bfr[n][0], acc[2 * (p4_)][n]);            \
            acc[2 * (p4_)][n] = MFMA_BF16(a0k1, bfr[n][1], acc[2 * (p4_)][n]);            \
            acc[2 * (p4_) + 1][n] = MFMA_BF16(a1k0, bfr[n][0], acc[2 * (p4_) + 1][n]);    \
            acc[2 * (p4_) + 1][n] = MFMA_BF16(a1k1, bfr[n][1], acc[2 * (p4_) + 1][n]);    \
        }                                                                                 \
        __builtin_amdgcn_s_setprio(0);                                                    \
        asm volatile("s_barrier" ::: "memory");                                           \
    } while (0)

    STAGE(0, 0, 0); STAGE(0, 0, 1); STAGE(0, 1, 0); STAGE(0, 1, 1);
    STAGE(1, 1, 0); STAGE(1, 1, 1);
    asm volatile("s_waitcnt vmcnt(4)" ::: "memory");
    asm volatile("s_barrier" ::: "memory");

    for (int i = 0; i < NT / 2; i++) {
        int t1 = 2 * i + 1;
        PHASE(0, 0, t1, 0, 0, 0);
        PHASE(0, 1, t1, 0, 1, 0);
        PHASE(0, 2, t1 + 1, 1, 0, 0);
        PHASE(0, 3, t1 + 1, 1, 1, 1);
        PHASE(1, 0, t1 + 1, 0, 0, 0);
        PHASE(1, 1, t1 + 1, 0, 1, 0);
        PHASE(1, 2, t1 + 2, 1, 0, 0);
        PHASE(1, 3, t1 + 2, 1, 1, 1);
    }
#undef PHASE
#undef STAGE

    int crow0 = bm * 256 + wm * 128;
    int ccol0 = bn * 256 + wn * 64;
#pragma unroll
    for (int m = 0; m < 8; m++) {
#pragma unroll
        for (int r = 0; r < 4; r++) {
            int row = crow0 + m * 16 + hl * 4 + r;
#pragma unroll
            for (int n = 0; n < 4; n++) {
                int col = ccol0 + n * 16 + ll;
                float val = acc[m][n][r];
                if (MODE == 0) {
                    Cb[(size_t)row * N + col] = f2bf(val);
                } else {
                    size_t idx = (size_t)row * N + col;
                    Cf[idx] = resid[idx] + val;
                }
            }
        }
    }
}

// ---------------- windowed block attention (band-limited, R5 proven) ----------------
// grid: B*H*NB blocks; 256 threads = 4 waves x 32 query rows.
// Per m-frag (16 queries at frag index m0 = 2w+mf), only key frags m0..m0+8 are unmasked.
// LDS: [0,32768) K [256 keys][64 dh] XOR-swizzled (reused as Vt [64][264] swizzled after QK^T);
//      [33792, 44032) per-wave P staging [32][40].
__global__ __launch_bounds__(256, 3) void attn_kernel(const unsigned short* __restrict__ qkv,
                                                      unsigned short* __restrict__ obuf) {
    constexpr int S = 4096, D = 1024, H = 16, W = 128, NB = 32;
    constexpr int TD = 3 * D;
    constexpr int PS = 40;

    __shared__ __align__(16) char smem[44032];
    unsigned short* KV = (unsigned short*)smem;

    int bid = blockIdx.x;
    int blk = bid % NB;
    int h = (bid / NB) % H;
    int b = bid / (NB * H);

    int tid = threadIdx.x, lane = tid & 63, w = tid >> 6;
    int hl = lane >> 4, ll = lane & 15;
    unsigned short* Ps = (unsigned short*)(smem + 33792) + w * 32 * PS;

    int kbase = blk * W - W;            // global s of extended key 0
    size_t rowbase = (size_t)(b * S);

    // ---- stage K [256][64] via async global_load_lds, source pre-swizzled ----
    {
        int lr = lane >> 3;                       // row within 8-row chunk
        int scb = ((lane & 7) ^ lr) * 16;         // swizzled source byte col
#pragma unroll
        for (int r = 0; r < 8; r++) {
            int row = r * 32 + w * 8 + lr;        // ext key index
            int s = kbase + row;
            s = s < 0 ? 0 : s;                    // clamp (blk 0: masked later, finite data)
            const char* src = (const char*)(qkv + (rowbase + s) * TD + D + h * 64) + scb;
            char* dst = smem + (size_t)(r * 32 + w * 8) * 128 + lane * 16;
            gload_lds16(src, dst);
        }
    }

    // ---- Q fragments ----
    s8v qf[2][2];
    {
        const unsigned short* qb = qkv + (rowbase + blk * W + w * 32) * TD + h * 64;
#pragma unroll
        for (int mf = 0; mf < 2; mf++)
#pragma unroll
            for (int ks = 0; ks < 2; ks++)
                qf[mf][ks] = *(const s8v*)(qb + (size_t)(mf * 16 + ll) * TD + ks * 32 + hl * 8);
    }

    // ---- prefetch V into regs: lane owns 8x8 block V[k0..k0+7][d0..d0+7] ----
    s8v vreg[8];
    {
        int k0 = w * 64 + (lane >> 3) * 8;
        int d0 = (lane & 7) * 8;
#pragma unroll
        for (int it = 0; it < 8; it++) {
            int s = kbase + k0 + it;
            s = s < 0 ? 0 : s;
            vreg[it] = *(const s8v*)(qkv + (rowbase + s) * TD + 2 * D + h * 64 + d0);
        }
    }
    __syncthreads();   // K in LDS (V regs also arrived)

    // ---- QK^T: band of 9 key frags per m-frag; kf shared across mf via 10-frag sweep ----
    f4v sc[2][9] = {};
    int g0 = w * 2;
    __builtin_amdgcn_s_setprio(1);
#pragma unroll
    for (int gi = 0; gi < 10; gi++) {
#pragma unroll
        for (int ks = 0; ks < 2; ks++) {
            int row = (g0 + gi) * 16 + ll;
            s8v kf = *(const s8v*)(smem + (size_t)row * 128 +
                                   (((unsigned)(ks * 64 + hl * 16)) ^ ((ll & 7) << 4)));
            if (gi < 9) sc[0][gi] = MFMA_BF16(qf[0][ks], kf, sc[0][gi]);
            if (gi > 0) sc[1][gi - 1] = MFMA_BF16(qf[1][ks], kf, sc[1][gi - 1]);
        }
    }
    __builtin_amdgcn_s_setprio(0);

    // ---- mask + scale + softmax (rows across 16 lanes of quarter-wave) ----
    float linv[2][4];
#pragma unroll
    for (int mf = 0; mf < 2; mf++) {
#pragma unroll
        for (int r = 0; r < 4; r++) {
            int ip = hl * 4 + r;                  // query pos within m-frag
            float mx = -1e30f;
#pragma unroll
            for (int nf = 0; nf < 9; nf++) {
                bool ok = (nf > 0 || ll > ip) && (nf < 8 || ll <= ip) &&
                          (blk > 0 || (g0 + mf + nf) >= 8);
                float sval = ok ? sc[mf][nf][r] * 0.125f : -1e30f;
                sc[mf][nf][r] = sval;
                mx = fmaxf(mx, sval);
            }
#pragma unroll
            for (int off = 1; off < 16; off <<= 1) mx = fmaxf(mx, __shfl_xor(mx, off, 64));
            float sum = 0.f;
#pragma unroll
            for (int nf = 0; nf < 9; nf++) {
                float p = __expf(sc[mf][nf][r] - mx);
                sc[mf][nf][r] = p;
                sum += p;
            }
#pragma unroll
            for (int off = 1; off < 16; off <<= 1) sum += __shfl_xor(sum, off, 64);
            linv[mf][r] = 1.f / sum;
        }
    }

    __syncthreads();   // all waves done reading K

    // ---- write V transposed: in-register 8x8 transpose, 8 x ds_write_b128 ----
    // Vt[d][k'] with k' = k ^ (((d>>3)&7)<<3); read side applies the same XOR.
    {
        int k0 = w * 64 + (lane >> 3) * 8;
        int d0 = (lane & 7) * 8;
#pragma unroll
        for (int e = 0; e < 8; e++) {
            int d = d0 + e;
            s8v tmp;
#pragma unroll
            for (int i = 0; i < 8; i++) tmp[i] = vreg[i][e];
            *(s8v*)(KV + d * 264 + (k0 ^ (((d >> 3) & 7) << 3))) = tmp;
        }
    }
    __syncthreads();   // Vt visible

    // ---- PV: 5 chunks of 32 keys starting at wave base w*32 ----
    f4v o[2][4] = {};
#pragma unroll
    for (int c = 0; c < 5; c++) {
#pragma unroll
        for (int mf = 0; mf < 2; mf++) {
#pragma unroll
            for (int j16 = 0; j16 < 2; j16++) {
                int nf = c * 2 + j16 - mf;
                int nfc = nf < 0 ? 0 : (nf > 8 ? 8 : nf);
#pragma unroll
                for (int r = 0; r < 4; r++) {
                    float val = (nf >= 0 && nf < 9) ? sc[mf][nfc][r] : 0.f;
                    Ps[(mf * 16 + hl * 4 + r) * PS + j16 * 16 + ll] = f2bf(val);
                }
            }
        }
        asm volatile("s_waitcnt lgkmcnt(0)" ::: "memory");
        s8v pa[2];
        pa[0] = *(const s8v*)(Ps + ll * PS + hl * 8);
        pa[1] = *(const s8v*)(Ps + (16 + ll) * PS + hl * 8);
        int cb = (w + c) * 32;
        __builtin_amdgcn_s_setprio(1);
#pragma unroll
        for (int nd = 0; nd < 4; nd++) {
            int d = nd * 16 + ll;
            int kk = (cb + hl * 8) ^ (((d >> 3) & 7) << 3);
            s8v vb = *(const s8v*)(KV + d * 264 + kk);
            o[0][nd] = MFMA_BF16(pa[0], vb, o[0][nd]);
            o[1][nd] = MFMA_BF16(pa[1], vb, o[1][nd]);
        }
        __builtin_amdgcn_s_setprio(0);
    }

    // ---- write O (bf16) ----
    unsigned short* ob = obuf + (rowbase + blk * W + w * 32) * D + h * 64;
#pragma unroll
    for (int mf = 0; mf < 2; mf++)
#pragma unroll
        for (int r = 0; r < 4; r++) {
            int row = mf * 16 + hl * 4 + r;
#pragma unroll
            for (int nd = 0; nd < 4; nd++)
                ob[(size_t)row * D + nd * 16 + ll] = f2bf(o[mf][nd][r] * linv[mf][r]);
        }
}

// ---------------- launch ----------------
extern "C" void kernel_launch(void* const* d_in, const int* in_sizes, int n_in,
                              void* d_out, int out_size, void* d_ws, size_t ws_size,
                              hipStream_t stream) {
    const float* x = (const float*)d_in[0];
    const float* g = (const float*)d_in[1];
    const float* Wqkv = (const float*)d_in[2];
    const float* Wo = (const float*)d_in[3];
    float* out = (float*)d_out;

    const int S = 4096, D = 1024, B = 4;
    const int M = B * S;  // 16384
    const int N3 = 3 * D; // 3072

    // workspace layout (bytes):
    //   [0, 6291456)            WqkvT bf16 [3072][1024]
    //   [6291456, 8388608)      WoT   bf16 [1024][1024]
    //   [8388608, 41943040)     xn    bf16 [16384][1024]  (reused as attention output)
    //   [41943040, 142606336)   qkv   bf16 [16384][3072]
    char* ws = (char*)d_ws;
    unsigned short* WqkvT = (unsigned short*)ws;
    unsigned short* WoT = (unsigned short*)(ws + 6291456);
    unsigned short* xn = (unsigned short*)(ws + 8388608);
    unsigned short* qkv = (unsigned short*)(ws + 41943040);

    transpose_cast_kernel<<<dim3((D / 32) * (N3 / 32) + (D / 32) * (D / 32)), dim3(256), 0,
                            stream>>>(Wqkv, WqkvT, Wo, WoT);
    rmsnorm_kernel<<<dim3(M), dim3(256), 0, stream>>>(x, g, xn);
    gemm256_kernel<0><<<dim3((M / 256) * (N3 / 256)), dim3(512), 0, stream>>>(
        xn, WqkvT, qkv, nullptr, nullptr, M, N3, D);
    attn_kernel<<<dim3(B * 16 * (S / 128)), dim3(256), 0, stream>>>(qkv, xn);
    gemm256_kernel<1><<<dim3((M / 256) * (D / 256)), dim3(512), 0, stream>>>(
        xn, WoT, nullptr, out, x, M, D, D);
}